// Round 10
// baseline (247.156 us; speedup 1.0000x reference)
//
#include <hip/hip_runtime.h>
#include <cstdint>
#include <cstddef>

// x[B=32, T=4096, N=256] fp32 -> z same shape.
// Refractory scan: spike at step t iff x>0 and t >= na; then na = t+6.
// Entry state q==k <=> first k steps of chunk blocked. q in [0,5].
//
// R10: R1/R6/R9 all land at total 235.4-235.5 despite three different
// phase-2 schemes => phase-2 was never the cost. Remaining suspect: one
// fat 1024-thread block per CU means block-wide barriers make each CU
// strictly single-phase (read XOR write), and chain stalls idle the whole
// CU. This round: same proven structure, but 512-thread blocks, 2
// independent blocks/CU (grid 512, PSUB=8, PG=16) so one block streams
// while the other waits -- block-level read/write pipelining.
#define BB 32
#define TT 4096
#define NNV 64        // float4 groups per row (N=256)
#define CC 32         // steps per chunk (one u32 bitmask per chain)
#define PSUB 8        // chunks per block (one per 64-lane wave)
#define PG 16         // chunk-groups per chain: T / (CC*PSUB)
#define NCH 256       // chains (N)

// Per-chunk entry->exit table from a 32-step sign bitmask.
// <=6 spikes per 32 steps (each advances na by 6): 6 branchless ctz iters.
__device__ __forceinline__ uint32_t tbl_from_mask(uint32_t m) {
    uint32_t tbl = 0;
    #pragma unroll
    for (int e = 0; e < 6; ++e) {
        int na = e;
        #pragma unroll
        for (int it = 0; it < 6; ++it) {
            const uint32_t r = (na < 32) ? (m >> na) : 0u;
            const int t = na + (r ? __builtin_ctz(r) : 0);
            na = r ? (t + 6) : na;
        }
        const int q = na > CC ? na - CC : 0;   // exit state in [0,5]
        tbl |= (uint32_t)q << (4 * e);
    }
    return tbl;
}

__global__ __launch_bounds__(512, 8) void refrac_fused(const float* __restrict__ x,
                                                       float* __restrict__ z,
                                                       uint8_t* __restrict__ msg) {
    const int tid = threadIdx.x;
    const int pg = blockIdx.x >> 5;   // chunk-group; lower pg dispatched first
    const int b  = blockIdx.x & 31;   // batch
    const int psub = tid >> 6;        // which of the 8 chunks (== wave id)
    const int n4 = tid & 63;          // float4 group along N
    const int p = pg * PSUB + psub;   // absolute chunk index

    const float4* __restrict__ xv = reinterpret_cast<const float4*>(x)
        + ((size_t)b * TT + (size_t)p * CC) * NNV + n4;

    // --- Phase 1: load + sign-bit extraction (contiguous 1 KB per wave) ---
    uint32_t cur[4] = {0u, 0u, 0u, 0u};
    #pragma unroll
    for (int jb = 0; jb < CC; jb += 8) {
        float4 buf[8];
        #pragma unroll
        for (int u = 0; u < 8; ++u)
            buf[u] = xv[(size_t)(jb + u) * NNV];
        #pragma unroll
        for (int u = 0; u < 8; ++u) {
            const int j = jb + u;
            cur[0] |= (buf[u].x > 0.0f) ? (1u << j) : 0u;
            cur[1] |= (buf[u].y > 0.0f) ? (1u << j) : 0u;
            cur[2] |= (buf[u].z > 0.0f) ? (1u << j) : 0u;
            cur[3] |= (buf[u].w > 0.0f) ? (1u << j) : 0u;
        }
    }

    __shared__ uint32_t tbl_lds[PSUB][NCH];  // 8 KB: 6 nibbles per chain
    __shared__ uint8_t  ent_lds[PSUB][NCH];  // 2 KB: resolved entry states

    #pragma unroll
    for (int c = 0; c < 4; ++c)
        tbl_lds[psub][n4 * 4 + c] = tbl_from_mask(cur[c]);
    __syncthreads();

    // --- Phase 2 (tid<256, thread n == chain n): serial chain hop ---
    if (tid < NCH) {
        const int n = tid;
        uint32_t t8[PSUB];                     // chunk tables in registers
        #pragma unroll
        for (int s = 0; s < PSUB; ++s) t8[s] = tbl_lds[s][n];

        int e = 0;
        if (pg > 0) {
            const uint8_t* inb = msg + (((size_t)b * PG + (pg - 1)) << 8) + n;
            uint32_t v;
            // bit7 set (poison 0xAA) => not ready; states <=5 are valid
            while ((v = __hip_atomic_load(inb, __ATOMIC_RELAXED,
                                          __HIP_MEMORY_SCOPE_AGENT)) & 0x80u)
                __builtin_amdgcn_s_sleep(1);
            e = (int)(v & 0xFu);
        }
        // Walk entry through the 8 chunks (registers only).
        #pragma unroll
        for (int s = 0; s < PSUB; ++s) {
            ent_lds[s][n] = (uint8_t)e;
            e = (int)((t8[s] >> (4 * e)) & 0xFu);
        }
        if (pg < PG - 1)
            __hip_atomic_store(msg + (((size_t)b * PG + pg) << 8) + n,
                               (uint8_t)e, __ATOMIC_RELAXED,
                               __HIP_MEMORY_SCOPE_AGENT);
    }
    __syncthreads();

    // --- Phase 3: emit z (contiguous 1 KB per wave, plain stores) ---
    float4* __restrict__ zv = reinterpret_cast<float4*>(z)
        + ((size_t)b * TT + (size_t)p * CC) * NNV + n4;

    const uint32_t e4 = *reinterpret_cast<const uint32_t*>(&ent_lds[psub][n4 * 4]);
    uint32_t spk[4];
    #pragma unroll
    for (int c = 0; c < 4; ++c) {
        const uint32_t m = cur[c];
        int na = (int)((e4 >> (8 * c)) & 0xFFu);
        uint32_t s = 0;
        #pragma unroll
        for (int it = 0; it < 6; ++it) {
            const uint32_t r = (na < 32) ? (m >> na) : 0u;
            const int t = na + (r ? __builtin_ctz(r) : 0);
            s |= r ? (1u << (t & 31)) : 0u;   // t < 32 whenever r != 0
            na = r ? (t + 6) : na;
        }
        spk[c] = s;
    }

    #pragma unroll
    for (int j = 0; j < CC; ++j) {
        float4 o;
        o.x = ((spk[0] >> j) & 1u) ? 1.0f : 0.0f;
        o.y = ((spk[1] >> j) & 1u) ? 1.0f : 0.0f;
        o.z = ((spk[2] >> j) & 1u) ? 1.0f : 0.0f;
        o.w = ((spk[3] >> j) & 1u) ? 1.0f : 0.0f;
        zv[(size_t)j * NNV] = o;
    }
}

extern "C" void kernel_launch(void* const* d_in, const int* in_sizes, int n_in,
                              void* d_out, int out_size, void* d_ws, size_t ws_size,
                              hipStream_t stream) {
    const float* x = (const float*)d_in[0];
    float* z = (float*)d_out;
    uint8_t* msg = (uint8_t*)d_ws;

    // Deterministic "not ready" poison (0xAA => bit7 set in every byte).
    hipMemsetAsync(d_ws, 0xAA, (size_t)BB * PG * NCH, stream);

    refrac_fused<<<dim3(BB * PG), 512, 0, stream>>>(x, z, msg);
}